// Round 1
// baseline (902.130 us; speedup 1.0000x reference)
//
#include <hip/hip_runtime.h>

#define NN 100000
#define EE 1600000

// ---------------- setup kernels ----------------

__global__ void k_zero_int(int* __restrict__ p, int n) {
    int i = blockIdx.x * 256 + threadIdx.x;
    if (i < n) p[i] = 0;
}

__global__ void k_count(const int* __restrict__ dst, int* __restrict__ cnt) {
    int e = blockIdx.x * 256 + threadIdx.x;
    if (e < EE) atomicAdd(&cnt[dst[e]], 1);
}

// deg = indegree + 1 (self loop); always >= 1 so the where(deg>0) is moot
__global__ void k_dis(const int* __restrict__ cnt, float* __restrict__ dis) {
    int i = blockIdx.x * 256 + threadIdx.x;
    if (i < NN) dis[i] = rsqrtf((float)(cnt[i] + 1));
}

// exclusive scan of cnt -> row_ptr, 1024 elems/block, block totals -> S
__global__ __launch_bounds__(1024) void k_scan1(const int* __restrict__ cnt,
                                                int* __restrict__ row_ptr,
                                                int* __restrict__ S) {
    __shared__ int sh[1024];
    int tid = threadIdx.x;
    int i = blockIdx.x * 1024 + tid;
    int v = (i < NN) ? cnt[i] : 0;
    sh[tid] = v;
    __syncthreads();
    for (int off = 1; off < 1024; off <<= 1) {
        int t = (tid >= off) ? sh[tid - off] : 0;
        __syncthreads();
        sh[tid] += t;
        __syncthreads();
    }
    if (i < NN) row_ptr[i] = sh[tid] - v;       // exclusive
    if (tid == 1023) S[blockIdx.x] = sh[tid];   // block total
}

__global__ void k_scan2(int* __restrict__ S, int nb) {
    if (blockIdx.x == 0 && threadIdx.x == 0) {
        int run = 0;
        for (int b = 0; b < nb; b++) { int t = S[b]; S[b] = run; run += t; }
    }
}

__global__ void k_scan3(int* __restrict__ row_ptr, int* __restrict__ cursor,
                        const int* __restrict__ S) {
    int i = blockIdx.x * 256 + threadIdx.x;
    if (i < NN) {
        int r = row_ptr[i] + S[i >> 10];
        row_ptr[i] = r;
        cursor[i] = r;
    }
}

// CSR fill: entry = {src, bits(norm)} grouped by dst
__global__ void k_fill(const int* __restrict__ src, const int* __restrict__ dst,
                       const float* __restrict__ dis, int* __restrict__ cursor,
                       int2* __restrict__ csr) {
    int e = blockIdx.x * 256 + threadIdx.x;
    if (e < EE) {
        int s = src[e], d = dst[e];
        int slot = atomicAdd(&cursor[d], 1);
        csr[slot] = make_int2(s, __float_as_int(dis[s] * dis[d]));
    }
}

// Wt[k*F + f] = W[f*128 + k]  (one-time 64KB transpose; coalesced reads)
__global__ void k_transpose(const float* __restrict__ W, float* __restrict__ Wt, int F) {
    int idx = blockIdx.x * 256 + threadIdx.x;
    if (idx < 128 * F) {
        int f = idx >> 7, k = idx & 127;
        Wt[k * F + f] = W[idx];
    }
}

// ---------------- GEMM: C[M,F] = A[M,128] @ Wt[128,F] (+bias) ----------------

__device__ __forceinline__ void fma4(float4& a, float s, const float4& w) {
    a.x += s * w.x; a.y += s * w.y; a.z += s * w.z; a.w += s * w.w;
}

template <int F>
__global__ __launch_bounds__(256) void k_gemm(const float* __restrict__ A,
                                              const float* __restrict__ Wt,
                                              const float* __restrict__ bias,
                                              float* __restrict__ Cout, int M) {
    constexpr int FG = F / 4;            // feature quads
    constexpr int NPB = (256 / FG) * 4;  // nodes per block (32 for F=128, 64 for F=64)
    int tid = threadIdx.x;
    int fg = tid % FG, ng = tid / FG;
    int f0 = fg * 4;
    int nbase = blockIdx.x * NPB + ng * 4;

    float4 acc[4];
#pragma unroll
    for (int i = 0; i < 4; i++) acc[i] = make_float4(0.f, 0.f, 0.f, 0.f);

    for (int k0 = 0; k0 < 128; k0 += 4) {
        float4 w0 = *(const float4*)&Wt[(k0 + 0) * F + f0];
        float4 w1 = *(const float4*)&Wt[(k0 + 1) * F + f0];
        float4 w2 = *(const float4*)&Wt[(k0 + 2) * F + f0];
        float4 w3 = *(const float4*)&Wt[(k0 + 3) * F + f0];
#pragma unroll
        for (int i = 0; i < 4; i++) {
            int n = nbase + i;
            int nc = (n < M) ? n : (M - 1);  // clamp: safe read, store is guarded
            float4 hv = *(const float4*)&A[(size_t)nc * 128 + k0];
            fma4(acc[i], hv.x, w0);
            fma4(acc[i], hv.y, w1);
            fma4(acc[i], hv.z, w2);
            fma4(acc[i], hv.w, w3);
        }
    }

    float4 bv = make_float4(0.f, 0.f, 0.f, 0.f);
    if (bias) bv = *(const float4*)&bias[f0];
#pragma unroll
    for (int i = 0; i < 4; i++) {
        int n = nbase + i;
        if (n < M) {
            float4 o = acc[i];
            o.x += bv.x; o.y += bv.y; o.z += bv.z; o.w += bv.w;
            *(float4*)&Cout[(size_t)n * F + f0] = o;
        }
    }
}

// ---------------- aggregation: one wave per node, lane owns 2 features ------

__global__ __launch_bounds__(256) void k_agg(const float* __restrict__ m,
                                             const int* __restrict__ row_ptr,
                                             const int* __restrict__ cnt,
                                             const int2* __restrict__ csr,
                                             const float* __restrict__ dis,
                                             const float* __restrict__ bias,
                                             const float* __restrict__ res,
                                             float* __restrict__ hout) {
    int wave = threadIdx.x >> 6;
    int lane = threadIdx.x & 63;
    int v = blockIdx.x * 4 + wave;
    if (v >= NN) return;
    int f0 = lane * 2;

    float2 acc = make_float2(0.f, 0.f);
    int start = row_ptr[v];
    int c = cnt[v];
    for (int i = 0; i < c; i++) {
        int2 ent = csr[start + i];
        float nrm = __int_as_float(ent.y);
        float2 mm = *(const float2*)&m[(size_t)ent.x * 128 + f0];
        acc.x += mm.x * nrm;
        acc.y += mm.y * nrm;
    }
    // self loop: norm = dis[v]^2
    float dv = dis[v];
    float self = dv * dv;
    float2 mv = *(const float2*)&m[(size_t)v * 128 + f0];
    acc.x += mv.x * self;
    acc.y += mv.y * self;
    // bias, relu, residual
    float2 bv = *(const float2*)&bias[f0];
    acc.x = fmaxf(acc.x + bv.x, 0.f);
    acc.y = fmaxf(acc.y + bv.y, 0.f);
    float2 rv = *(const float2*)&res[(size_t)v * 128 + f0];
    acc.x += rv.x;
    acc.y += rv.y;
    *(float2*)&hout[(size_t)v * 128 + f0] = acc;
}

// ---------------- host ----------------

extern "C" void kernel_launch(void* const* d_in, const int* in_sizes, int n_in,
                              void* d_out, int out_size, void* d_ws, size_t ws_size,
                              hipStream_t stream) {
    const float* x   = (const float*)d_in[0];
    const int*   ei  = (const int*)d_in[1];   // [2,E] int32
    const float* W1  = (const float*)d_in[2];
    const float* b1  = (const float*)d_in[3];
    const float* W2  = (const float*)d_in[4];
    const float* b2  = (const float*)d_in[5];
    const float* WL  = (const float*)d_in[6];
    const float* bl  = (const float*)d_in[7];
    float* out = (float*)d_out;

    const int* esrc = ei;
    const int* edst = ei + EE;

    char* w = (char*)d_ws;
    auto alloc = [&](size_t bytes) -> char* {
        char* p = w;
        w += (bytes + 255) & ~(size_t)255;
        return p;
    };
    int*   cnt     = (int*)alloc((size_t)NN * 4);
    int*   row_ptr = (int*)alloc((size_t)NN * 4);
    int*   cursor  = (int*)alloc((size_t)NN * 4);
    float* dis     = (float*)alloc((size_t)NN * 4);
    int*   S       = (int*)alloc(1024 * 4);
    int2*  csr     = (int2*)alloc((size_t)EE * 8);
    float* W1t     = (float*)alloc(128 * 128 * 4);
    float* W2t     = (float*)alloc(128 * 128 * 4);
    float* WLt     = (float*)alloc(128 * 64 * 4);
    float* A       = (float*)alloc((size_t)NN * 128 * 4);  // m buffer
    float* B       = (float*)alloc((size_t)NN * 128 * 4);  // h buffer

    const int nb_n   = (NN + 255) / 256;
    const int nb_e   = (EE + 255) / 256;
    const int nb_s1  = (NN + 1023) / 1024;  // 98

    // degree + normalization
    k_zero_int<<<nb_n, 256, 0, stream>>>(cnt, NN);
    k_count<<<nb_e, 256, 0, stream>>>(edst, cnt);
    k_dis<<<nb_n, 256, 0, stream>>>(cnt, dis);

    // CSR build
    k_scan1<<<nb_s1, 1024, 0, stream>>>(cnt, row_ptr, S);
    k_scan2<<<1, 64, 0, stream>>>(S, nb_s1);
    k_scan3<<<nb_n, 256, 0, stream>>>(row_ptr, cursor, S);
    k_fill<<<nb_e, 256, 0, stream>>>(esrc, edst, dis, cursor, csr);

    // weight transposes
    k_transpose<<<(128 * 128 + 255) / 256, 256, 0, stream>>>(W1, W1t, 128);
    k_transpose<<<(128 * 128 + 255) / 256, 256, 0, stream>>>(W2, W2t, 128);
    k_transpose<<<(128 * 64 + 255) / 256, 256, 0, stream>>>(WL, WLt, 64);

    const int nb_g128 = (NN + 31) / 32;    // 3125
    const int nb_g64  = (NN + 63) / 64;    // 1563
    const int nb_agg  = (NN + 3) / 4;      // 25000

    // layer 1: m1 = x @ W1.T ; h1 = relu(agg(m1)+b1) + x  -> B
    k_gemm<128><<<nb_g128, 256, 0, stream>>>(x, W1t, nullptr, A, NN);
    k_agg<<<nb_agg, 256, 0, stream>>>(A, row_ptr, cnt, csr, dis, b1, x, B);

    // layer 2: m2 = h1 @ W2.T ; h2 = relu(agg(m2)+b2) + h1 -> B (in place)
    k_gemm<128><<<nb_g128, 256, 0, stream>>>(B, W2t, nullptr, A, NN);
    k_agg<<<nb_agg, 256, 0, stream>>>(A, row_ptr, cnt, csr, dis, b2, B, B);

    // head: out = h2 @ Wlin.T + blin
    k_gemm<64><<<nb_g64, 256, 0, stream>>>(B, WLt, bl, out, NN);
}

// Round 2
// 683.827 us; speedup vs baseline: 1.3192x; 1.3192x over previous
//
#include <hip/hip_runtime.h>

#define NN 100000
#define EE 1600000

typedef short bf16x8 __attribute__((ext_vector_type(8)));
typedef float floatx4 __attribute__((ext_vector_type(4)));

__device__ __forceinline__ unsigned short f2bf(float f) {
    unsigned int u = __float_as_uint(f);
    u = (u + 0x7FFF + ((u >> 16) & 1)) >> 16;   // round-to-nearest-even
    return (unsigned short)u;
}
__device__ __forceinline__ float bf2f_lo(unsigned int packed) {
    return __uint_as_float(packed << 16);
}
__device__ __forceinline__ float bf2f_hi(unsigned int packed) {
    return __uint_as_float(packed & 0xFFFF0000u);
}

// ---------------- setup kernels ----------------

__global__ void k_zero_int(int* __restrict__ p, int n) {
    int i = blockIdx.x * 256 + threadIdx.x;
    if (i < n) p[i] = 0;
}

__global__ void k_count(const int* __restrict__ dst, int* __restrict__ cnt) {
    int e = blockIdx.x * 256 + threadIdx.x;
    if (e < EE) atomicAdd(&cnt[dst[e]], 1);
}

__global__ void k_dis(const int* __restrict__ cnt, float* __restrict__ dis) {
    int i = blockIdx.x * 256 + threadIdx.x;
    if (i < NN) dis[i] = rsqrtf((float)(cnt[i] + 1));
}

// fp32 -> bf16 elementwise (n must be a multiple of 4)
__global__ void k_cvt(const float* __restrict__ in, unsigned short* __restrict__ out, int n) {
    int i = (blockIdx.x * 256 + threadIdx.x) * 4;
    if (i < n) {
        float4 f = *(const float4*)&in[i];
        unsigned short r[4] = {f2bf(f.x), f2bf(f.y), f2bf(f.z), f2bf(f.w)};
        *(ushort2*)&out[i]     = make_ushort2(r[0], r[1]);
        *(ushort2*)&out[i + 2] = make_ushort2(r[2], r[3]);
    }
}

// exclusive scan of cnt -> row_ptr, 1024 elems/block, block totals -> S
__global__ __launch_bounds__(1024) void k_scan1(const int* __restrict__ cnt,
                                                int* __restrict__ row_ptr,
                                                int* __restrict__ S) {
    __shared__ int sh[1024];
    int tid = threadIdx.x;
    int i = blockIdx.x * 1024 + tid;
    int v = (i < NN) ? cnt[i] : 0;
    sh[tid] = v;
    __syncthreads();
    for (int off = 1; off < 1024; off <<= 1) {
        int t = (tid >= off) ? sh[tid - off] : 0;
        __syncthreads();
        sh[tid] += t;
        __syncthreads();
    }
    if (i < NN) row_ptr[i] = sh[tid] - v;       // exclusive
    if (tid == 1023) S[blockIdx.x] = sh[tid];   // block total
}

// exclusive scan of the 98 block totals, one block
__global__ __launch_bounds__(128) void k_scan2(int* __restrict__ S, int nb) {
    __shared__ int sh[128];
    int tid = threadIdx.x;
    int v = (tid < nb) ? S[tid] : 0;
    sh[tid] = v;
    __syncthreads();
    for (int off = 1; off < 128; off <<= 1) {
        int t = (tid >= off) ? sh[tid - off] : 0;
        __syncthreads();
        sh[tid] += t;
        __syncthreads();
    }
    if (tid < nb) S[tid] = sh[tid] - v;
}

__global__ void k_scan3(int* __restrict__ row_ptr, int* __restrict__ cursor,
                        const int* __restrict__ S) {
    int i = blockIdx.x * 256 + threadIdx.x;
    if (i < NN) {
        int r = row_ptr[i] + S[i >> 10];
        row_ptr[i] = r;
        cursor[i] = r;
    }
}

// CSR fill: entry = {src, bits(norm)} grouped by dst
__global__ void k_fill(const int* __restrict__ src, const int* __restrict__ dst,
                       const float* __restrict__ dis, int* __restrict__ cursor,
                       int2* __restrict__ csr) {
    int e = blockIdx.x * 256 + threadIdx.x;
    if (e < EE) {
        int s = src[e], d = dst[e];
        int slot = atomicAdd(&cursor[d], 1);
        csr[slot] = make_int2(s, __float_as_int(dis[s] * dis[d]));
    }
}

// ---------------- MFMA GEMM: C[M,F] = A[M,128] @ W[F,128].T (+bias) ----------
// A bf16 row-major, W bf16 [F][128] (original layout: B-operand wants W[f][k]
// contiguous in k). One wave -> 16 nodes x F features via 16x16x32 bf16 MFMA.
// Verified layouts (learn_hip m89/m120): A[m=lane&15][k=quad*8+j],
// B[n=lane&15][k=quad*8+j], C/D col=lane&15 row=quad*4+reg.

template <int F, bool OUT_BF16>
__global__ __launch_bounds__(256) void k_gemm_mfma(const unsigned short* __restrict__ A,
                                                   const unsigned short* __restrict__ Wb,
                                                   const float* __restrict__ bias,
                                                   void* __restrict__ Cout, int M) {
    int wave = threadIdx.x >> 6, lane = threadIdx.x & 63;
    int quad = lane >> 4, r16 = lane & 15;
    int node0 = blockIdx.x * 64 + wave * 16;

    int arow = node0 + r16;
    if (arow >= M) arow = M - 1;                 // clamp read; stores guarded
    const unsigned short* Ap = A + (size_t)arow * 128 + quad * 8;
    bf16x8 af[4];
#pragma unroll
    for (int ks = 0; ks < 4; ks++) af[ks] = *(const bf16x8*)(Ap + ks * 32);

    constexpr int NFT = F / 16;
#pragma unroll
    for (int ft = 0; ft < NFT; ft++) {
        int f = ft * 16 + r16;
        const unsigned short* Bp = Wb + (size_t)f * 128 + quad * 8;
        floatx4 acc = {0.f, 0.f, 0.f, 0.f};
#pragma unroll
        for (int ks = 0; ks < 4; ks++) {
            bf16x8 bfr = *(const bf16x8*)(Bp + ks * 32);
            acc = __builtin_amdgcn_mfma_f32_16x16x32_bf16(af[ks], bfr, acc, 0, 0, 0);
        }
        float bv = bias ? bias[f] : 0.f;
#pragma unroll
        for (int rg = 0; rg < 4; rg++) {
            int node = node0 + quad * 4 + rg;
            if (node < M) {
                float o = acc[rg] + bv;
                if (OUT_BF16)
                    ((unsigned short*)Cout)[(size_t)node * F + f] = f2bf(o);
                else
                    ((float*)Cout)[(size_t)node * F + f] = o;
            }
        }
    }
}

// ---------------- aggregation: one wave per node, lane owns 2 features ------
// m, res, hout all bf16; accumulate fp32.

__global__ __launch_bounds__(256) void k_agg(const unsigned short* __restrict__ m,
                                             const int* __restrict__ row_ptr,
                                             const int* __restrict__ cnt,
                                             const int2* __restrict__ csr,
                                             const float* __restrict__ dis,
                                             const float* __restrict__ bias,
                                             const unsigned short* __restrict__ res,
                                             unsigned short* __restrict__ hout) {
    int wave = threadIdx.x >> 6;
    int lane = threadIdx.x & 63;
    int v = blockIdx.x * 4 + wave;
    if (v >= NN) return;
    int f0 = lane * 2;

    float ax = 0.f, ay = 0.f;
    int start = row_ptr[v];
    int c = cnt[v];
    for (int i = 0; i < c; i++) {
        int2 ent = csr[start + i];                 // broadcast (same addr all lanes)
        float nrm = __int_as_float(ent.y);
        unsigned int mm = *(const unsigned int*)&m[(size_t)ent.x * 128 + f0];
        ax = fmaf(bf2f_lo(mm), nrm, ax);
        ay = fmaf(bf2f_hi(mm), nrm, ay);
    }
    // self loop: norm = dis[v]^2
    float dv = dis[v];
    float self = dv * dv;
    unsigned int mv = *(const unsigned int*)&m[(size_t)v * 128 + f0];
    ax = fmaf(bf2f_lo(mv), self, ax);
    ay = fmaf(bf2f_hi(mv), self, ay);
    // bias, relu, residual
    float2 bv = *(const float2*)&bias[f0];
    ax = fmaxf(ax + bv.x, 0.f);
    ay = fmaxf(ay + bv.y, 0.f);
    unsigned int rv = *(const unsigned int*)&res[(size_t)v * 128 + f0];
    ax += bf2f_lo(rv);
    ay += bf2f_hi(rv);
    *(ushort2*)&hout[(size_t)v * 128 + f0] = make_ushort2(f2bf(ax), f2bf(ay));
}

// ---------------- host ----------------

extern "C" void kernel_launch(void* const* d_in, const int* in_sizes, int n_in,
                              void* d_out, int out_size, void* d_ws, size_t ws_size,
                              hipStream_t stream) {
    const float* x   = (const float*)d_in[0];
    const int*   ei  = (const int*)d_in[1];   // [2,E] int32
    const float* W1  = (const float*)d_in[2];
    const float* b1  = (const float*)d_in[3];
    const float* W2  = (const float*)d_in[4];
    const float* b2  = (const float*)d_in[5];
    const float* WL  = (const float*)d_in[6];
    const float* bl  = (const float*)d_in[7];
    float* out = (float*)d_out;

    const int* esrc = ei;
    const int* edst = ei + EE;

    char* w = (char*)d_ws;
    auto alloc = [&](size_t bytes) -> char* {
        char* p = w;
        w += (bytes + 255) & ~(size_t)255;
        return p;
    };
    int*   cnt     = (int*)alloc((size_t)NN * 4);
    int*   row_ptr = (int*)alloc((size_t)NN * 4);
    int*   cursor  = (int*)alloc((size_t)NN * 4);
    float* dis     = (float*)alloc((size_t)NN * 4);
    int*   S       = (int*)alloc(1024 * 4);
    int2*  csr     = (int2*)alloc((size_t)EE * 8);
    unsigned short* W1b = (unsigned short*)alloc(128 * 128 * 2);
    unsigned short* W2b = (unsigned short*)alloc(128 * 128 * 2);
    unsigned short* WLb = (unsigned short*)alloc(64 * 128 * 2);
    unsigned short* xb  = (unsigned short*)alloc((size_t)NN * 128 * 2);
    unsigned short* A   = (unsigned short*)alloc((size_t)NN * 128 * 2);  // m (bf16)
    unsigned short* B   = (unsigned short*)alloc((size_t)NN * 128 * 2);  // h (bf16)

    const int nb_n  = (NN + 255) / 256;
    const int nb_e  = (EE + 255) / 256;
    const int nb_s1 = (NN + 1023) / 1024;  // 98

    // degree + normalization
    k_zero_int<<<nb_n, 256, 0, stream>>>(cnt, NN);
    k_count<<<nb_e, 256, 0, stream>>>(edst, cnt);
    k_dis<<<nb_n, 256, 0, stream>>>(cnt, dis);

    // CSR build
    k_scan1<<<nb_s1, 1024, 0, stream>>>(cnt, row_ptr, S);
    k_scan2<<<1, 128, 0, stream>>>(S, nb_s1);
    k_scan3<<<nb_n, 256, 0, stream>>>(row_ptr, cursor, S);
    k_fill<<<nb_e, 256, 0, stream>>>(esrc, edst, dis, cursor, csr);

    // bf16 conversions (x and weights; biases stay fp32)
    k_cvt<<<(NN * 128 / 4 + 255) / 256, 256, 0, stream>>>(x, xb, NN * 128);
    k_cvt<<<(128 * 128 / 4 + 255) / 256, 256, 0, stream>>>(W1, W1b, 128 * 128);
    k_cvt<<<(128 * 128 / 4 + 255) / 256, 256, 0, stream>>>(W2, W2b, 128 * 128);
    k_cvt<<<(64 * 128 / 4 + 255) / 256, 256, 0, stream>>>(WL, WLb, 64 * 128);

    const int nb_g   = (NN + 63) / 64;     // 1563
    const int nb_agg = (NN + 3) / 4;       // 25000

    // layer 1: m1 = xb @ W1.T ; h1 = relu(agg(m1)+b1) + xb  -> B
    k_gemm_mfma<128, true><<<nb_g, 256, 0, stream>>>(xb, W1b, nullptr, A, NN);
    k_agg<<<nb_agg, 256, 0, stream>>>(A, row_ptr, cnt, csr, dis, b1, xb, B);

    // layer 2: m2 = h1 @ W2.T ; h2 = relu(agg(m2)+b2) + h1 -> B (in place)
    k_gemm_mfma<128, true><<<nb_g, 256, 0, stream>>>(B, W2b, nullptr, A, NN);
    k_agg<<<nb_agg, 256, 0, stream>>>(A, row_ptr, cnt, csr, dis, b2, B, B);

    // head: out = h2 @ Wlin.T + blin (fp32 out)
    k_gemm_mfma<64, false><<<nb_g, 256, 0, stream>>>(B, WLb, bl, out, NN);
}

// Round 3
// 472.061 us; speedup vs baseline: 1.9110x; 1.4486x over previous
//
#include <hip/hip_runtime.h>

#define NN 100000
#define EE 1600000

typedef short bf16x8 __attribute__((ext_vector_type(8)));
typedef float floatx4 __attribute__((ext_vector_type(4)));

__device__ __forceinline__ unsigned short f2bf(float f) {
    unsigned int u = __float_as_uint(f);
    u = (u + 0x7FFF + ((u >> 16) & 1)) >> 16;   // round-to-nearest-even
    return (unsigned short)u;
}
__device__ __forceinline__ float bf2f_lo(unsigned int packed) {
    return __uint_as_float(packed << 16);
}
__device__ __forceinline__ float bf2f_hi(unsigned int packed) {
    return __uint_as_float(packed & 0xFFFF0000u);
}

// ---------------- setup kernels ----------------

__global__ void k_zero_int(int* __restrict__ p, int n) {
    int i = blockIdx.x * 256 + threadIdx.x;
    if (i < n) p[i] = 0;
}

__global__ void k_count(const int* __restrict__ dst, int* __restrict__ cnt) {
    int e = blockIdx.x * 256 + threadIdx.x;
    if (e < EE) atomicAdd(&cnt[dst[e]], 1);
}

// exclusive scan of cnt -> row_ptr, 1024 elems/block, block totals -> S
__global__ __launch_bounds__(1024) void k_scan1(const int* __restrict__ cnt,
                                                int* __restrict__ row_ptr,
                                                int* __restrict__ S) {
    __shared__ int sh[1024];
    int tid = threadIdx.x;
    int i = blockIdx.x * 1024 + tid;
    int v = (i < NN) ? cnt[i] : 0;
    sh[tid] = v;
    __syncthreads();
    for (int off = 1; off < 1024; off <<= 1) {
        int t = (tid >= off) ? sh[tid - off] : 0;
        __syncthreads();
        sh[tid] += t;
        __syncthreads();
    }
    if (i < NN) row_ptr[i] = sh[tid] - v;       // exclusive
    if (tid == 1023) S[blockIdx.x] = sh[tid];   // block total
}

// exclusive scan of the 98 block totals, one block
__global__ __launch_bounds__(128) void k_scan2(int* __restrict__ S, int nb) {
    __shared__ int sh[128];
    int tid = threadIdx.x;
    int v = (tid < nb) ? S[tid] : 0;
    sh[tid] = v;
    __syncthreads();
    for (int off = 1; off < 128; off <<= 1) {
        int t = (tid >= off) ? sh[tid - off] : 0;
        __syncthreads();
        sh[tid] += t;
        __syncthreads();
    }
    if (tid < nb) S[tid] = sh[tid] - v;
}

// finalize row_ptr/cursor; also compute dis = rsqrt(deg) (fused, needs cnt)
__global__ void k_scan3(int* __restrict__ row_ptr, int* __restrict__ cursor,
                        const int* __restrict__ S, const int* __restrict__ cnt,
                        float* __restrict__ dis) {
    int i = blockIdx.x * 256 + threadIdx.x;
    if (i < NN) {
        int r = row_ptr[i] + S[i >> 10];
        row_ptr[i] = r;
        cursor[i] = r;
        dis[i] = rsqrtf((float)(cnt[i] + 1));
    }
}

// CSR fill: entry = {src, bits(norm)} grouped by dst
__global__ void k_fill(const int* __restrict__ src, const int* __restrict__ dst,
                       const float* __restrict__ dis, int* __restrict__ cursor,
                       int2* __restrict__ csr) {
    int e = blockIdx.x * 256 + threadIdx.x;
    if (e < EE) {
        int s = src[e], d = dst[e];
        int slot = atomicAdd(&cursor[d], 1);
        csr[slot] = make_int2(s, __float_as_int(dis[s] * dis[d]));
    }
}

// all three weight matrices fp32->bf16 in one launch (quad-granular)
__global__ void k_cvt_w(const float* __restrict__ W1, const float* __restrict__ W2,
                        const float* __restrict__ WL,
                        unsigned short* __restrict__ W1b, unsigned short* __restrict__ W2b,
                        unsigned short* __restrict__ WLb) {
    int i = blockIdx.x * 256 + threadIdx.x;   // quad index
    const float* src; unsigned short* dst; int off;
    if (i < 4096)       { src = W1; dst = W1b; off = i; }
    else if (i < 8192)  { src = W2; dst = W2b; off = i - 4096; }
    else if (i < 10240) { src = WL; dst = WLb; off = i - 8192; }
    else return;
    float4 f = ((const float4*)src)[off];
    unsigned short r0 = f2bf(f.x), r1 = f2bf(f.y), r2 = f2bf(f.z), r3 = f2bf(f.w);
    ((ushort2*)dst)[off * 2]     = make_ushort2(r0, r1);
    ((ushort2*)dst)[off * 2 + 1] = make_ushort2(r2, r3);
}

// ---------------- MFMA GEMM: C[M,F] = A[M,128] @ W[F,128].T (+bias) ----------
// A row-major (fp32 or bf16), W bf16 [F][128]. One wave -> 16 nodes x F.
// Layouts (learn_hip m89): A[m=lane&15][k=quad*8+j], B[n=lane&15][k=quad*8+j],
// C/D col=lane&15 row=quad*4+reg.

template <int F, bool A_F32, bool OUT_BF16>
__global__ __launch_bounds__(256) void k_gemm_mfma(const void* __restrict__ A_,
                                                   const unsigned short* __restrict__ Wb,
                                                   const float* __restrict__ bias,
                                                   void* __restrict__ Cout, int M) {
    int wave = threadIdx.x >> 6, lane = threadIdx.x & 63;
    int quad = lane >> 4, r16 = lane & 15;
    int node0 = blockIdx.x * 64 + wave * 16;

    int arow = node0 + r16;
    if (arow >= M) arow = M - 1;                 // clamp read; stores guarded

    bf16x8 af[4];
    if (A_F32) {
        const float* Ap = (const float*)A_ + (size_t)arow * 128 + quad * 8;
#pragma unroll
        for (int ks = 0; ks < 4; ks++) {
            float4 x0 = *(const float4*)(Ap + ks * 32);
            float4 x1 = *(const float4*)(Ap + ks * 32 + 4);
            bf16x8 t;
            t[0] = (short)f2bf(x0.x); t[1] = (short)f2bf(x0.y);
            t[2] = (short)f2bf(x0.z); t[3] = (short)f2bf(x0.w);
            t[4] = (short)f2bf(x1.x); t[5] = (short)f2bf(x1.y);
            t[6] = (short)f2bf(x1.z); t[7] = (short)f2bf(x1.w);
            af[ks] = t;
        }
    } else {
        const unsigned short* Ap = (const unsigned short*)A_ + (size_t)arow * 128 + quad * 8;
#pragma unroll
        for (int ks = 0; ks < 4; ks++) af[ks] = *(const bf16x8*)(Ap + ks * 32);
    }

    constexpr int NFT = F / 16;
#pragma unroll
    for (int ft = 0; ft < NFT; ft++) {
        int f = ft * 16 + r16;
        const unsigned short* Bp = Wb + (size_t)f * 128 + quad * 8;
        floatx4 acc = {0.f, 0.f, 0.f, 0.f};
#pragma unroll
        for (int ks = 0; ks < 4; ks++) {
            bf16x8 bfr = *(const bf16x8*)(Bp + ks * 32);
            acc = __builtin_amdgcn_mfma_f32_16x16x32_bf16(af[ks], bfr, acc, 0, 0, 0);
        }
        float bv = bias ? bias[f] : 0.f;
#pragma unroll
        for (int rg = 0; rg < 4; rg++) {
            int node = node0 + quad * 4 + rg;
            if (node < M) {
                float o = acc[rg] + bv;
                if (OUT_BF16)
                    ((unsigned short*)Cout)[(size_t)node * F + f] = f2bf(o);
                else
                    ((float*)Cout)[(size_t)node * F + f] = o;
            }
        }
    }
}

// ---------------- aggregation ------------------------------------------------
// One wave per node. Lane owns 8 features (16B uint4); 16 lanes cover a 256B
// row, so ONE wave-load gathers 4 edges; batch x2 -> 8 gathers in flight.
// Cross-group (4 groups) reduction via shfl_xor at the end.

template <bool RES_F32>
__global__ __launch_bounds__(256) void k_agg(const unsigned short* __restrict__ m,
                                             const int* __restrict__ row_ptr,
                                             const int* __restrict__ cnt,
                                             const int2* __restrict__ csr,
                                             const float* __restrict__ dis,
                                             const float* __restrict__ bias,
                                             const void* __restrict__ res_,
                                             unsigned short* __restrict__ hout) {
    int wave = threadIdx.x >> 6;
    int lane = threadIdx.x & 63;
    int v = blockIdx.x * 4 + wave;
    if (v >= NN) return;
    int g = lane >> 4;            // edge slot within batch (0..3)
    int fl = (lane & 15) * 8;     // 8 features per lane

    float acc[8];
#pragma unroll
    for (int j = 0; j < 8; j++) acc[j] = 0.f;

    int start = row_ptr[v];
    int c = cnt[v];

    for (int base = 0; base < c; base += 8) {
        int i0 = base + g, i1 = base + 4 + g;
        bool p0 = i0 < c, p1 = i1 < c;
        int2 e0 = csr[start + (p0 ? i0 : 0)];
        int2 e1 = csr[start + (p1 ? i1 : 0)];
        float n0 = p0 ? __int_as_float(e0.y) : 0.f;
        float n1 = p1 ? __int_as_float(e1.y) : 0.f;
        int s0 = p0 ? e0.x : v;
        int s1 = p1 ? e1.x : v;
        uint4 r0 = *(const uint4*)&m[(size_t)s0 * 128 + fl];
        uint4 r1 = *(const uint4*)&m[(size_t)s1 * 128 + fl];
        acc[0] = fmaf(bf2f_lo(r0.x), n0, acc[0]);
        acc[1] = fmaf(bf2f_hi(r0.x), n0, acc[1]);
        acc[2] = fmaf(bf2f_lo(r0.y), n0, acc[2]);
        acc[3] = fmaf(bf2f_hi(r0.y), n0, acc[3]);
        acc[4] = fmaf(bf2f_lo(r0.z), n0, acc[4]);
        acc[5] = fmaf(bf2f_hi(r0.z), n0, acc[5]);
        acc[6] = fmaf(bf2f_lo(r0.w), n0, acc[6]);
        acc[7] = fmaf(bf2f_hi(r0.w), n0, acc[7]);
        acc[0] = fmaf(bf2f_lo(r1.x), n1, acc[0]);
        acc[1] = fmaf(bf2f_hi(r1.x), n1, acc[1]);
        acc[2] = fmaf(bf2f_lo(r1.y), n1, acc[2]);
        acc[3] = fmaf(bf2f_hi(r1.y), n1, acc[3]);
        acc[4] = fmaf(bf2f_lo(r1.z), n1, acc[4]);
        acc[5] = fmaf(bf2f_hi(r1.z), n1, acc[5]);
        acc[6] = fmaf(bf2f_lo(r1.w), n1, acc[6]);
        acc[7] = fmaf(bf2f_hi(r1.w), n1, acc[7]);
    }

    // reduce the 4 lane-groups (XOR bits 5 and 4 of lane id)
#pragma unroll
    for (int j = 0; j < 8; j++) {
        acc[j] += __shfl_xor(acc[j], 32);
        acc[j] += __shfl_xor(acc[j], 16);
    }

    // tail: self-loop + bias + relu + residual (all lanes compute; g==0 stores)
    const size_t vrow = (size_t)v * 128 + fl;
    float dv = dis[v];
    float self = dv * dv;
    uint4 mv = *(const uint4*)&m[vrow];
    float4 b0 = *(const float4*)&bias[fl];
    float4 b1 = *(const float4*)&bias[fl + 4];
    float mvf[8] = {bf2f_lo(mv.x), bf2f_hi(mv.x), bf2f_lo(mv.y), bf2f_hi(mv.y),
                    bf2f_lo(mv.z), bf2f_hi(mv.z), bf2f_lo(mv.w), bf2f_hi(mv.w)};
    float bb[8] = {b0.x, b0.y, b0.z, b0.w, b1.x, b1.y, b1.z, b1.w};
    float rr[8];
    if (RES_F32) {
        const float* rp = (const float*)res_ + (size_t)v * 128 + fl;
        float4 q0 = *(const float4*)rp;
        float4 q1 = *(const float4*)(rp + 4);
        rr[0] = q0.x; rr[1] = q0.y; rr[2] = q0.z; rr[3] = q0.w;
        rr[4] = q1.x; rr[5] = q1.y; rr[6] = q1.z; rr[7] = q1.w;
    } else {
        uint4 rv = *(const uint4*)((const unsigned short*)res_ + vrow);
        rr[0] = bf2f_lo(rv.x); rr[1] = bf2f_hi(rv.x);
        rr[2] = bf2f_lo(rv.y); rr[3] = bf2f_hi(rv.y);
        rr[4] = bf2f_lo(rv.z); rr[5] = bf2f_hi(rv.z);
        rr[6] = bf2f_lo(rv.w); rr[7] = bf2f_hi(rv.w);
    }
    unsigned short po[8];
#pragma unroll
    for (int j = 0; j < 8; j++) {
        float t = fmaxf(fmaf(mvf[j], self, acc[j]) + bb[j], 0.f) + rr[j];
        po[j] = f2bf(t);
    }
    if (g == 0) {
        uint4 o;
        o.x = (unsigned)po[0] | ((unsigned)po[1] << 16);
        o.y = (unsigned)po[2] | ((unsigned)po[3] << 16);
        o.z = (unsigned)po[4] | ((unsigned)po[5] << 16);
        o.w = (unsigned)po[6] | ((unsigned)po[7] << 16);
        *(uint4*)&hout[vrow] = o;
    }
}

// ---------------- host ----------------

extern "C" void kernel_launch(void* const* d_in, const int* in_sizes, int n_in,
                              void* d_out, int out_size, void* d_ws, size_t ws_size,
                              hipStream_t stream) {
    const float* x   = (const float*)d_in[0];
    const int*   ei  = (const int*)d_in[1];   // [2,E] int32
    const float* W1  = (const float*)d_in[2];
    const float* b1  = (const float*)d_in[3];
    const float* W2  = (const float*)d_in[4];
    const float* b2  = (const float*)d_in[5];
    const float* WL  = (const float*)d_in[6];
    const float* bl  = (const float*)d_in[7];
    float* out = (float*)d_out;

    const int* esrc = ei;
    const int* edst = ei + EE;

    char* w = (char*)d_ws;
    auto alloc = [&](size_t bytes) -> char* {
        char* p = w;
        w += (bytes + 255) & ~(size_t)255;
        return p;
    };
    int*   cnt     = (int*)alloc((size_t)NN * 4);
    int*   row_ptr = (int*)alloc((size_t)NN * 4);
    int*   cursor  = (int*)alloc((size_t)NN * 4);
    float* dis     = (float*)alloc((size_t)NN * 4);
    int*   S       = (int*)alloc(1024 * 4);
    int2*  csr     = (int2*)alloc((size_t)EE * 8);
    unsigned short* W1b = (unsigned short*)alloc(128 * 128 * 2);
    unsigned short* W2b = (unsigned short*)alloc(128 * 128 * 2);
    unsigned short* WLb = (unsigned short*)alloc(64 * 128 * 2);
    unsigned short* A   = (unsigned short*)alloc((size_t)NN * 128 * 2);  // m (bf16)
    unsigned short* B   = (unsigned short*)alloc((size_t)NN * 128 * 2);  // h (bf16)

    const int nb_n  = (NN + 255) / 256;
    const int nb_e  = (EE + 255) / 256;
    const int nb_s1 = (NN + 1023) / 1024;  // 98

    // degree
    k_zero_int<<<nb_n, 256, 0, stream>>>(cnt, NN);
    k_count<<<nb_e, 256, 0, stream>>>(edst, cnt);

    // CSR build (+dis fused into scan3)
    k_scan1<<<nb_s1, 1024, 0, stream>>>(cnt, row_ptr, S);
    k_scan2<<<1, 128, 0, stream>>>(S, nb_s1);
    k_scan3<<<nb_n, 256, 0, stream>>>(row_ptr, cursor, S, cnt, dis);
    k_fill<<<nb_e, 256, 0, stream>>>(esrc, edst, dis, cursor, csr);

    // weights fp32 -> bf16 (single launch)
    k_cvt_w<<<40, 256, 0, stream>>>(W1, W2, WL, W1b, W2b, WLb);

    const int nb_g   = (NN + 63) / 64;     // 1563
    const int nb_agg = (NN + 3) / 4;       // 25000

    // layer 1: m1 = x @ W1.T (x read as fp32); h1 = relu(agg(m1)+b1) + x -> B
    k_gemm_mfma<128, true, true><<<nb_g, 256, 0, stream>>>(x, W1b, nullptr, A, NN);
    k_agg<true><<<nb_agg, 256, 0, stream>>>(A, row_ptr, cnt, csr, dis, b1, x, B);

    // layer 2: m2 = h1 @ W2.T ; h2 = relu(agg(m2)+b2) + h1 -> B (in place)
    k_gemm_mfma<128, false, true><<<nb_g, 256, 0, stream>>>(B, W2b, nullptr, A, NN);
    k_agg<false><<<nb_agg, 256, 0, stream>>>(A, row_ptr, cnt, csr, dis, b2, B, B);

    // head: out = h2 @ Wlin.T + blin (fp32 out)
    k_gemm_mfma<64, false, false><<<nb_g, 256, 0, stream>>>(B, WLb, bl, out, NN);
}

// Round 4
// 432.667 us; speedup vs baseline: 2.0850x; 1.0910x over previous
//
#include <hip/hip_runtime.h>

#define NN 100000
#define EE 1600000

typedef short bf16x8 __attribute__((ext_vector_type(8)));
typedef float floatx4 __attribute__((ext_vector_type(4)));

__device__ __forceinline__ unsigned short f2bf(float f) {
    unsigned int u = __float_as_uint(f);
    u = (u + 0x7FFF + ((u >> 16) & 1)) >> 16;   // round-to-nearest-even
    return (unsigned short)u;
}
__device__ __forceinline__ float bf2f_lo(unsigned int packed) {
    return __uint_as_float(packed << 16);
}
__device__ __forceinline__ float bf2f_hi(unsigned int packed) {
    return __uint_as_float(packed & 0xFFFF0000u);
}

// ---------------- setup kernels ----------------

__global__ void k_zero_int(int* __restrict__ p, int n) {
    int i = blockIdx.x * 256 + threadIdx.x;
    if (i < n) p[i] = 0;
}

// rank[e] = arrival index of edge e at its destination; cnt[d] = indegree.
// Atomic is random/L2-hot but the rank write is coalesced.
__global__ void k_count_rank(const int* __restrict__ dst, int* __restrict__ cnt,
                             int* __restrict__ rank) {
    int e4 = (blockIdx.x * 256 + threadIdx.x) * 4;
    if (e4 < EE) {   // EE % 4 == 0, so all four lanes of the int4 are valid
        int4 d = *(const int4*)&dst[e4];
        int4 r;
        r.x = atomicAdd(&cnt[d.x], 1);
        r.y = atomicAdd(&cnt[d.y], 1);
        r.z = atomicAdd(&cnt[d.z], 1);
        r.w = atomicAdd(&cnt[d.w], 1);
        *(int4*)&rank[e4] = r;
    }
}

// exclusive scan of cnt -> row_ptr, 1024 elems/block, block totals -> S
__global__ __launch_bounds__(1024) void k_scan1(const int* __restrict__ cnt,
                                                int* __restrict__ row_ptr,
                                                int* __restrict__ S) {
    __shared__ int sh[1024];
    int tid = threadIdx.x;
    int i = blockIdx.x * 1024 + tid;
    int v = (i < NN) ? cnt[i] : 0;
    sh[tid] = v;
    __syncthreads();
    for (int off = 1; off < 1024; off <<= 1) {
        int t = (tid >= off) ? sh[tid - off] : 0;
        __syncthreads();
        sh[tid] += t;
        __syncthreads();
    }
    if (i < NN) row_ptr[i] = sh[tid] - v;       // exclusive
    if (tid == 1023) S[blockIdx.x] = sh[tid];   // block total
}

// exclusive scan of the 98 block totals, one block
__global__ __launch_bounds__(128) void k_scan2(int* __restrict__ S, int nb) {
    __shared__ int sh[128];
    int tid = threadIdx.x;
    int v = (tid < nb) ? S[tid] : 0;
    sh[tid] = v;
    __syncthreads();
    for (int off = 1; off < 128; off <<= 1) {
        int t = (tid >= off) ? sh[tid - off] : 0;
        __syncthreads();
        sh[tid] += t;
        __syncthreads();
    }
    if (tid < nb) S[tid] = sh[tid] - v;
}

// finalize row_ptr, pack {row_ptr,cnt} for agg, compute dis = rsqrt(deg)
__global__ void k_scan3(int* __restrict__ row_ptr, int2* __restrict__ rc,
                        const int* __restrict__ S, const int* __restrict__ cnt,
                        float* __restrict__ dis) {
    int i = blockIdx.x * 256 + threadIdx.x;
    if (i < NN) {
        int c = cnt[i];
        int r = row_ptr[i] + S[i >> 10];
        row_ptr[i] = r;
        rc[i] = make_int2(r, c);
        dis[i] = rsqrtf((float)(c + 1));
    }
}

// CSR place: no atomic, no dependent chain — fire-and-forget scattered stores
__global__ void k_fill2(const int* __restrict__ src, const int* __restrict__ dst,
                        const int* __restrict__ rank, const int* __restrict__ row_ptr,
                        int* __restrict__ csr) {
    int e4 = (blockIdx.x * 256 + threadIdx.x) * 4;
    if (e4 < EE) {
        int4 s = *(const int4*)&src[e4];
        int4 d = *(const int4*)&dst[e4];
        int4 r = *(const int4*)&rank[e4];
        csr[row_ptr[d.x] + r.x] = s.x;
        csr[row_ptr[d.y] + r.y] = s.y;
        csr[row_ptr[d.z] + r.z] = s.z;
        csr[row_ptr[d.w] + r.w] = s.w;
    }
}

// all three weight matrices fp32->bf16 in one launch (quad-granular)
__global__ void k_cvt_w(const float* __restrict__ W1, const float* __restrict__ W2,
                        const float* __restrict__ WL,
                        unsigned short* __restrict__ W1b, unsigned short* __restrict__ W2b,
                        unsigned short* __restrict__ WLb) {
    int i = blockIdx.x * 256 + threadIdx.x;   // quad index
    const float* src; unsigned short* dst; int off;
    if (i < 4096)       { src = W1; dst = W1b; off = i; }
    else if (i < 8192)  { src = W2; dst = W2b; off = i - 4096; }
    else if (i < 10240) { src = WL; dst = WLb; off = i - 8192; }
    else return;
    float4 f = ((const float4*)src)[off];
    unsigned short r0 = f2bf(f.x), r1 = f2bf(f.y), r2 = f2bf(f.z), r3 = f2bf(f.w);
    ((ushort2*)dst)[off * 2]     = make_ushort2(r0, r1);
    ((ushort2*)dst)[off * 2 + 1] = make_ushort2(r2, r3);
}

// ---------------- MFMA GEMM: C[M,F] = A[M,128] @ W[F,128].T (+bias) ----------
// A row-major (fp32 or bf16), W bf16 [F][128]. One wave -> 16 nodes x F.
// Layouts (learn_hip m89): A[m=lane&15][k=quad*8+j], B[n=lane&15][k=quad*8+j],
// C/D col=lane&15 row=quad*4+reg.

template <int F, bool A_F32, bool OUT_BF16>
__global__ __launch_bounds__(256) void k_gemm_mfma(const void* __restrict__ A_,
                                                   const unsigned short* __restrict__ Wb,
                                                   const float* __restrict__ bias,
                                                   void* __restrict__ Cout, int M) {
    int wave = threadIdx.x >> 6, lane = threadIdx.x & 63;
    int quad = lane >> 4, r16 = lane & 15;
    int node0 = blockIdx.x * 64 + wave * 16;

    int arow = node0 + r16;
    if (arow >= M) arow = M - 1;                 // clamp read; stores guarded

    bf16x8 af[4];
    if (A_F32) {
        const float* Ap = (const float*)A_ + (size_t)arow * 128 + quad * 8;
#pragma unroll
        for (int ks = 0; ks < 4; ks++) {
            float4 x0 = *(const float4*)(Ap + ks * 32);
            float4 x1 = *(const float4*)(Ap + ks * 32 + 4);
            bf16x8 t;
            t[0] = (short)f2bf(x0.x); t[1] = (short)f2bf(x0.y);
            t[2] = (short)f2bf(x0.z); t[3] = (short)f2bf(x0.w);
            t[4] = (short)f2bf(x1.x); t[5] = (short)f2bf(x1.y);
            t[6] = (short)f2bf(x1.z); t[7] = (short)f2bf(x1.w);
            af[ks] = t;
        }
    } else {
        const unsigned short* Ap = (const unsigned short*)A_ + (size_t)arow * 128 + quad * 8;
#pragma unroll
        for (int ks = 0; ks < 4; ks++) af[ks] = *(const bf16x8*)(Ap + ks * 32);
    }

    constexpr int NFT = F / 16;
#pragma unroll
    for (int ft = 0; ft < NFT; ft++) {
        int f = ft * 16 + r16;
        const unsigned short* Bp = Wb + (size_t)f * 128 + quad * 8;
        floatx4 acc = {0.f, 0.f, 0.f, 0.f};
#pragma unroll
        for (int ks = 0; ks < 4; ks++) {
            bf16x8 bfr = *(const bf16x8*)(Bp + ks * 32);
            acc = __builtin_amdgcn_mfma_f32_16x16x32_bf16(af[ks], bfr, acc, 0, 0, 0);
        }
        float bv = bias ? bias[f] : 0.f;
#pragma unroll
        for (int rg = 0; rg < 4; rg++) {
            int node = node0 + quad * 4 + rg;
            if (node < M) {
                float o = acc[rg] + bv;
                if (OUT_BF16)
                    ((unsigned short*)Cout)[(size_t)node * F + f] = f2bf(o);
                else
                    ((float*)Cout)[(size_t)node * F + f] = o;
            }
        }
    }
}

// ---------------- aggregation ------------------------------------------------
// One wave per node. Lane owns 8 features (16B uint4); 16 lanes cover a 256B
// row, so ONE wave-load gathers 4 edges; batch x2 -> 8 gathers in flight.
// csr holds src only; accumulate sum' = sum_s m[s]*dis[s] + m[v]*dis[v], then
// out = relu(dis[v]*sum' + bias) + res.

template <bool RES_F32>
__global__ __launch_bounds__(256) void k_agg(const unsigned short* __restrict__ m,
                                             const int2* __restrict__ rc,
                                             const int* __restrict__ csr,
                                             const float* __restrict__ dis,
                                             const float* __restrict__ bias,
                                             const void* __restrict__ res_,
                                             unsigned short* __restrict__ hout) {
    int wave = threadIdx.x >> 6;
    int lane = threadIdx.x & 63;
    int v = blockIdx.x * 4 + wave;
    if (v >= NN) return;
    int g = lane >> 4;            // edge slot within batch (0..3)
    int fl = (lane & 15) * 8;     // 8 features per lane

    float acc[8];
#pragma unroll
    for (int j = 0; j < 8; j++) acc[j] = 0.f;

    int2 rcv = rc[v];
    int start = rcv.x;
    int c = rcv.y;

    for (int base = 0; base < c; base += 8) {
        int i0 = base + g, i1 = base + 4 + g;
        bool p0 = i0 < c, p1 = i1 < c;
        int s0 = csr[start + (p0 ? i0 : 0)];   // broadcast within group
        int s1 = csr[start + (p1 ? i1 : 0)];
        if (!p0) s0 = v;
        if (!p1) s1 = v;
        float n0 = p0 ? dis[s0] : 0.f;          // broadcast, L2-hot 400KB table
        float n1 = p1 ? dis[s1] : 0.f;
        uint4 r0 = *(const uint4*)&m[(size_t)s0 * 128 + fl];
        uint4 r1 = *(const uint4*)&m[(size_t)s1 * 128 + fl];
        acc[0] = fmaf(bf2f_lo(r0.x), n0, acc[0]);
        acc[1] = fmaf(bf2f_hi(r0.x), n0, acc[1]);
        acc[2] = fmaf(bf2f_lo(r0.y), n0, acc[2]);
        acc[3] = fmaf(bf2f_hi(r0.y), n0, acc[3]);
        acc[4] = fmaf(bf2f_lo(r0.z), n0, acc[4]);
        acc[5] = fmaf(bf2f_hi(r0.z), n0, acc[5]);
        acc[6] = fmaf(bf2f_lo(r0.w), n0, acc[6]);
        acc[7] = fmaf(bf2f_hi(r0.w), n0, acc[7]);
        acc[0] = fmaf(bf2f_lo(r1.x), n1, acc[0]);
        acc[1] = fmaf(bf2f_hi(r1.x), n1, acc[1]);
        acc[2] = fmaf(bf2f_lo(r1.y), n1, acc[2]);
        acc[3] = fmaf(bf2f_hi(r1.y), n1, acc[3]);
        acc[4] = fmaf(bf2f_lo(r1.z), n1, acc[4]);
        acc[5] = fmaf(bf2f_hi(r1.z), n1, acc[5]);
        acc[6] = fmaf(bf2f_lo(r1.w), n1, acc[6]);
        acc[7] = fmaf(bf2f_hi(r1.w), n1, acc[7]);
    }

    // reduce the 4 lane-groups (XOR bits 5 and 4 of lane id)
#pragma unroll
    for (int j = 0; j < 8; j++) {
        acc[j] += __shfl_xor(acc[j], 32);
        acc[j] += __shfl_xor(acc[j], 16);
    }

    // tail: self-loop + bias + relu + residual (all lanes compute; g==0 stores)
    const size_t vrow = (size_t)v * 128 + fl;
    float dv = dis[v];
    uint4 mv = *(const uint4*)&m[vrow];
    float4 b0 = *(const float4*)&bias[fl];
    float4 b1 = *(const float4*)&bias[fl + 4];
    float mvf[8] = {bf2f_lo(mv.x), bf2f_hi(mv.x), bf2f_lo(mv.y), bf2f_hi(mv.y),
                    bf2f_lo(mv.z), bf2f_hi(mv.z), bf2f_lo(mv.w), bf2f_hi(mv.w)};
    float bb[8] = {b0.x, b0.y, b0.z, b0.w, b1.x, b1.y, b1.z, b1.w};
    float rr[8];
    if (RES_F32) {
        const float* rp = (const float*)res_ + (size_t)v * 128 + fl;
        float4 q0 = *(const float4*)rp;
        float4 q1 = *(const float4*)(rp + 4);
        rr[0] = q0.x; rr[1] = q0.y; rr[2] = q0.z; rr[3] = q0.w;
        rr[4] = q1.x; rr[5] = q1.y; rr[6] = q1.z; rr[7] = q1.w;
    } else {
        uint4 rv = *(const uint4*)((const unsigned short*)res_ + vrow);
        rr[0] = bf2f_lo(rv.x); rr[1] = bf2f_hi(rv.x);
        rr[2] = bf2f_lo(rv.y); rr[3] = bf2f_hi(rv.y);
        rr[4] = bf2f_lo(rv.z); rr[5] = bf2f_hi(rv.z);
        rr[6] = bf2f_lo(rv.w); rr[7] = bf2f_hi(rv.w);
    }
    unsigned short po[8];
#pragma unroll
    for (int j = 0; j < 8; j++) {
        float sum = fmaf(mvf[j], dv, acc[j]);           // + self*dis[v]
        float t = fmaxf(fmaf(sum, dv, bb[j]), 0.f) + rr[j];
        po[j] = f2bf(t);
    }
    if (g == 0) {
        uint4 o;
        o.x = (unsigned)po[0] | ((unsigned)po[1] << 16);
        o.y = (unsigned)po[2] | ((unsigned)po[3] << 16);
        o.z = (unsigned)po[4] | ((unsigned)po[5] << 16);
        o.w = (unsigned)po[6] | ((unsigned)po[7] << 16);
        *(uint4*)&hout[vrow] = o;
    }
}

// ---------------- host ----------------

extern "C" void kernel_launch(void* const* d_in, const int* in_sizes, int n_in,
                              void* d_out, int out_size, void* d_ws, size_t ws_size,
                              hipStream_t stream) {
    const float* x   = (const float*)d_in[0];
    const int*   ei  = (const int*)d_in[1];   // [2,E] int32
    const float* W1  = (const float*)d_in[2];
    const float* b1  = (const float*)d_in[3];
    const float* W2  = (const float*)d_in[4];
    const float* b2  = (const float*)d_in[5];
    const float* WL  = (const float*)d_in[6];
    const float* bl  = (const float*)d_in[7];
    float* out = (float*)d_out;

    const int* esrc = ei;
    const int* edst = ei + EE;

    char* w = (char*)d_ws;
    auto alloc = [&](size_t bytes) -> char* {
        char* p = w;
        w += (bytes + 255) & ~(size_t)255;
        return p;
    };
    int*   cnt     = (int*)alloc((size_t)NN * 4);
    int*   row_ptr = (int*)alloc((size_t)NN * 4);
    int2*  rc      = (int2*)alloc((size_t)NN * 8);
    float* dis     = (float*)alloc((size_t)NN * 4);
    int*   S       = (int*)alloc(1024 * 4);
    int*   rank    = (int*)alloc((size_t)EE * 4);
    int*   csr     = (int*)alloc((size_t)EE * 4);
    unsigned short* W1b = (unsigned short*)alloc(128 * 128 * 2);
    unsigned short* W2b = (unsigned short*)alloc(128 * 128 * 2);
    unsigned short* WLb = (unsigned short*)alloc(64 * 128 * 2);
    unsigned short* A   = (unsigned short*)alloc((size_t)NN * 128 * 2);  // m (bf16)
    unsigned short* B   = (unsigned short*)alloc((size_t)NN * 128 * 2);  // h (bf16)

    const int nb_n  = (NN + 255) / 256;
    const int nb_e4 = (EE / 4 + 255) / 256;
    const int nb_s1 = (NN + 1023) / 1024;  // 98

    // degree + per-edge arrival rank
    k_zero_int<<<nb_n, 256, 0, stream>>>(cnt, NN);
    k_count_rank<<<nb_e4, 256, 0, stream>>>(edst, cnt, rank);

    // row_ptr scan (+rc pack, +dis)
    k_scan1<<<nb_s1, 1024, 0, stream>>>(cnt, row_ptr, S);
    k_scan2<<<1, 128, 0, stream>>>(S, nb_s1);
    k_scan3<<<nb_n, 256, 0, stream>>>(row_ptr, rc, S, cnt, dis);

    // CSR place (no atomics)
    k_fill2<<<nb_e4, 256, 0, stream>>>(esrc, edst, rank, row_ptr, csr);

    // weights fp32 -> bf16 (single launch)
    k_cvt_w<<<40, 256, 0, stream>>>(W1, W2, WL, W1b, W2b, WLb);

    const int nb_g   = (NN + 63) / 64;     // 1563
    const int nb_agg = (NN + 3) / 4;       // 25000

    // layer 1: m1 = x @ W1.T (x read as fp32); h1 = relu(agg(m1)+b1) + x -> B
    k_gemm_mfma<128, true, true><<<nb_g, 256, 0, stream>>>(x, W1b, nullptr, A, NN);
    k_agg<true><<<nb_agg, 256, 0, stream>>>(A, rc, csr, dis, b1, x, B);

    // layer 2: m2 = h1 @ W2.T ; h2 = relu(agg(m2)+b2) + h1 -> B (in place)
    k_gemm_mfma<128, false, true><<<nb_g, 256, 0, stream>>>(B, W2b, nullptr, A, NN);
    k_agg<false><<<nb_agg, 256, 0, stream>>>(A, rc, csr, dis, b2, B, B);

    // head: out = h2 @ Wlin.T + blin (fp32 out)
    k_gemm_mfma<64, false, false><<<nb_g, 256, 0, stream>>>(B, WLb, bl, out, NN);
}

// Round 5
// 422.303 us; speedup vs baseline: 2.1362x; 1.0245x over previous
//
#include <hip/hip_runtime.h>

#define NN 100000
#define EE 1600000

typedef short bf16x8 __attribute__((ext_vector_type(8)));
typedef float floatx4 __attribute__((ext_vector_type(4)));

__device__ __forceinline__ unsigned short f2bf(float f) {
    unsigned int u = __float_as_uint(f);
    u = (u + 0x7FFF + ((u >> 16) & 1)) >> 16;   // round-to-nearest-even
    return (unsigned short)u;
}
__device__ __forceinline__ float bf2f_lo(unsigned int packed) {
    return __uint_as_float(packed << 16);
}
__device__ __forceinline__ float bf2f_hi(unsigned int packed) {
    return __uint_as_float(packed & 0xFFFF0000u);
}

// ---------------- setup kernels ----------------

__global__ void k_zero_int(int* __restrict__ p, int n) {
    int i = blockIdx.x * 256 + threadIdx.x;
    if (i < n) p[i] = 0;
}

// rank[e] = arrival index of edge e at its destination; cnt[d] = indegree.
// 8 independent atomics per thread (latency-bound: atomicAdd must return).
__global__ void k_count_rank(const int* __restrict__ dst, int* __restrict__ cnt,
                             int* __restrict__ rank) {
    int e8 = (blockIdx.x * 256 + threadIdx.x) * 8;
    if (e8 < EE) {   // EE % 8 == 0
        int4 d0 = *(const int4*)&dst[e8];
        int4 d1 = *(const int4*)&dst[e8 + 4];
        int4 r0, r1;
        r0.x = atomicAdd(&cnt[d0.x], 1);
        r0.y = atomicAdd(&cnt[d0.y], 1);
        r0.z = atomicAdd(&cnt[d0.z], 1);
        r0.w = atomicAdd(&cnt[d0.w], 1);
        r1.x = atomicAdd(&cnt[d1.x], 1);
        r1.y = atomicAdd(&cnt[d1.y], 1);
        r1.z = atomicAdd(&cnt[d1.z], 1);
        r1.w = atomicAdd(&cnt[d1.w], 1);
        *(int4*)&rank[e8]     = r0;
        *(int4*)&rank[e8 + 4] = r1;
    }
}

// exclusive scan of cnt -> row_ptr, 1024 elems/block, block totals -> S
__global__ __launch_bounds__(1024) void k_scan1(const int* __restrict__ cnt,
                                                int* __restrict__ row_ptr,
                                                int* __restrict__ S) {
    __shared__ int sh[1024];
    int tid = threadIdx.x;
    int i = blockIdx.x * 1024 + tid;
    int v = (i < NN) ? cnt[i] : 0;
    sh[tid] = v;
    __syncthreads();
    for (int off = 1; off < 1024; off <<= 1) {
        int t = (tid >= off) ? sh[tid - off] : 0;
        __syncthreads();
        sh[tid] += t;
        __syncthreads();
    }
    if (i < NN) row_ptr[i] = sh[tid] - v;       // exclusive
    if (tid == 1023) S[blockIdx.x] = sh[tid];   // block total
}

// exclusive scan of the 98 block totals, one block
__global__ __launch_bounds__(128) void k_scan2(int* __restrict__ S, int nb) {
    __shared__ int sh[128];
    int tid = threadIdx.x;
    int v = (tid < nb) ? S[tid] : 0;
    sh[tid] = v;
    __syncthreads();
    for (int off = 1; off < 128; off <<= 1) {
        int t = (tid >= off) ? sh[tid - off] : 0;
        __syncthreads();
        sh[tid] += t;
        __syncthreads();
    }
    if (tid < nb) S[tid] = sh[tid] - v;
}

// finalize row_ptr, pack {row_ptr,cnt}, dis = rsqrt(deg); zero row NN of A
__global__ void k_scan3(int* __restrict__ row_ptr, int2* __restrict__ rc,
                        const int* __restrict__ S, const int* __restrict__ cnt,
                        float* __restrict__ dis, unsigned int* __restrict__ Azero) {
    int i = blockIdx.x * 256 + threadIdx.x;
    if (i < NN) {
        int c = cnt[i];
        int r = row_ptr[i] + S[i >> 10];
        row_ptr[i] = r;
        rc[i] = make_int2(r, c);
        dis[i] = rsqrtf((float)(c + 1));
    }
    if (blockIdx.x == 0 && threadIdx.x < 64) Azero[threadIdx.x] = 0;  // 256B zero row
}

// CSR place: no atomic, no dependent chain — fire-and-forget scattered stores
__global__ void k_fill2(const int* __restrict__ src, const int* __restrict__ dst,
                        const int* __restrict__ rank, const int* __restrict__ row_ptr,
                        int* __restrict__ csr) {
    int e8 = (blockIdx.x * 256 + threadIdx.x) * 8;
    if (e8 < EE) {
        int4 s0 = *(const int4*)&src[e8];
        int4 s1 = *(const int4*)&src[e8 + 4];
        int4 d0 = *(const int4*)&dst[e8];
        int4 d1 = *(const int4*)&dst[e8 + 4];
        int4 r0 = *(const int4*)&rank[e8];
        int4 r1 = *(const int4*)&rank[e8 + 4];
        csr[row_ptr[d0.x] + r0.x] = s0.x;
        csr[row_ptr[d0.y] + r0.y] = s0.y;
        csr[row_ptr[d0.z] + r0.z] = s0.z;
        csr[row_ptr[d0.w] + r0.w] = s0.w;
        csr[row_ptr[d1.x] + r1.x] = s1.x;
        csr[row_ptr[d1.y] + r1.y] = s1.y;
        csr[row_ptr[d1.z] + r1.z] = s1.z;
        csr[row_ptr[d1.w] + r1.w] = s1.w;
    }
}

// all three weight matrices fp32->bf16 in one launch (quad-granular)
__global__ void k_cvt_w(const float* __restrict__ W1, const float* __restrict__ W2,
                        const float* __restrict__ WL,
                        unsigned short* __restrict__ W1b, unsigned short* __restrict__ W2b,
                        unsigned short* __restrict__ WLb) {
    int i = blockIdx.x * 256 + threadIdx.x;   // quad index
    const float* src; unsigned short* dst; int off;
    if (i < 4096)       { src = W1; dst = W1b; off = i; }
    else if (i < 8192)  { src = W2; dst = W2b; off = i - 4096; }
    else if (i < 10240) { src = WL; dst = WLb; off = i - 8192; }
    else return;
    float4 f = ((const float4*)src)[off];
    unsigned short r0 = f2bf(f.x), r1 = f2bf(f.y), r2 = f2bf(f.z), r3 = f2bf(f.w);
    ((ushort2*)dst)[off * 2]     = make_ushort2(r0, r1);
    ((ushort2*)dst)[off * 2 + 1] = make_ushort2(r2, r3);
}

// ---------------- MFMA GEMM: C[M,F] = A[M,128] @ W[F,128].T -------------------
// Optionally scales output rows by scale[row] (folds dis[src] into messages).
// Layouts (learn_hip m89): A[m=lane&15][k=quad*8+j], B[n=lane&15][k=quad*8+j],
// C/D col=lane&15 row=quad*4+reg.

template <int F, bool A_F32, bool OUT_BF16, bool SCALE>
__global__ __launch_bounds__(256) void k_gemm_mfma(const void* __restrict__ A_,
                                                   const unsigned short* __restrict__ Wb,
                                                   const float* __restrict__ bias,
                                                   const float* __restrict__ scale,
                                                   void* __restrict__ Cout, int M) {
    int wave = threadIdx.x >> 6, lane = threadIdx.x & 63;
    int quad = lane >> 4, r16 = lane & 15;
    int node0 = blockIdx.x * 64 + wave * 16;

    int arow = node0 + r16;
    if (arow >= M) arow = M - 1;                 // clamp read; stores guarded

    bf16x8 af[4];
    if (A_F32) {
        const float* Ap = (const float*)A_ + (size_t)arow * 128 + quad * 8;
#pragma unroll
        for (int ks = 0; ks < 4; ks++) {
            float4 x0 = *(const float4*)(Ap + ks * 32);
            float4 x1 = *(const float4*)(Ap + ks * 32 + 4);
            bf16x8 t;
            t[0] = (short)f2bf(x0.x); t[1] = (short)f2bf(x0.y);
            t[2] = (short)f2bf(x0.z); t[3] = (short)f2bf(x0.w);
            t[4] = (short)f2bf(x1.x); t[5] = (short)f2bf(x1.y);
            t[6] = (short)f2bf(x1.z); t[7] = (short)f2bf(x1.w);
            af[ks] = t;
        }
    } else {
        const unsigned short* Ap = (const unsigned short*)A_ + (size_t)arow * 128 + quad * 8;
#pragma unroll
        for (int ks = 0; ks < 4; ks++) af[ks] = *(const bf16x8*)(Ap + ks * 32);
    }

    // per-output-row scale factors (same 4 rows for every ft iteration)
    float dsc[4];
#pragma unroll
    for (int rg = 0; rg < 4; rg++) {
        int node = node0 + quad * 4 + rg;
        dsc[rg] = SCALE ? scale[(node < M) ? node : (M - 1)] : 1.f;
    }

    constexpr int NFT = F / 16;
#pragma unroll
    for (int ft = 0; ft < NFT; ft++) {
        int f = ft * 16 + r16;
        const unsigned short* Bp = Wb + (size_t)f * 128 + quad * 8;
        floatx4 acc = {0.f, 0.f, 0.f, 0.f};
#pragma unroll
        for (int ks = 0; ks < 4; ks++) {
            bf16x8 bfr = *(const bf16x8*)(Bp + ks * 32);
            acc = __builtin_amdgcn_mfma_f32_16x16x32_bf16(af[ks], bfr, acc, 0, 0, 0);
        }
        float bv = bias ? bias[f] : 0.f;
#pragma unroll
        for (int rg = 0; rg < 4; rg++) {
            int node = node0 + quad * 4 + rg;
            if (node < M) {
                float o = acc[rg];
                if (SCALE) o *= dsc[rg];
                o += bv;
                if (OUT_BF16)
                    ((unsigned short*)Cout)[(size_t)node * F + f] = f2bf(o);
                else
                    ((float*)Cout)[(size_t)node * F + f] = o;
            }
        }
    }
}

// ---------------- aggregation ------------------------------------------------
// m is pre-scaled by dis[src] ("m'"). One wave per node; lane owns 8 features
// (16B); 16 lanes cover a 256B row; batch of 16 edges -> 4 independent gathers
// per lane per iteration. Inactive slots gather the zero row (index NN).
// out = relu(dis[v] * (sum m'[s] + m'[v]) + bias) + res.

template <bool RES_F32>
__global__ __launch_bounds__(256) void k_agg(const unsigned short* __restrict__ m,
                                             const int2* __restrict__ rc,
                                             const int* __restrict__ csr,
                                             const float* __restrict__ dis,
                                             const float* __restrict__ bias,
                                             const void* __restrict__ res_,
                                             unsigned short* __restrict__ hout) {
    int wave = threadIdx.x >> 6;
    int lane = threadIdx.x & 63;
    int v = blockIdx.x * 4 + wave;
    if (v >= NN) return;
    int g = lane >> 4;            // edge slot within batch (0..3)
    int fl = (lane & 15) * 8;     // 8 features per lane

    float acc[8];
#pragma unroll
    for (int j = 0; j < 8; j++) acc[j] = 0.f;

    int2 rcv = rc[v];
    int start = rcv.x;
    int c = rcv.y;

    for (int base = 0; base < c; base += 16) {
        int i0 = base + g, i1 = base + 4 + g, i2 = base + 8 + g, i3 = base + 12 + g;
        bool p0 = i0 < c, p1 = i1 < c, p2 = i2 < c, p3 = i3 < c;
        int s0 = csr[start + (p0 ? i0 : 0)];
        int s1 = csr[start + (p1 ? i1 : 0)];
        int s2 = csr[start + (p2 ? i2 : 0)];
        int s3 = csr[start + (p3 ? i3 : 0)];
        if (!p0) s0 = NN;          // zero row
        if (!p1) s1 = NN;
        if (!p2) s2 = NN;
        if (!p3) s3 = NN;
        uint4 r0 = *(const uint4*)&m[(size_t)s0 * 128 + fl];
        uint4 r1 = *(const uint4*)&m[(size_t)s1 * 128 + fl];
        uint4 r2 = *(const uint4*)&m[(size_t)s2 * 128 + fl];
        uint4 r3 = *(const uint4*)&m[(size_t)s3 * 128 + fl];
#pragma unroll
        for (int q = 0; q < 4; q++) {
            uint4 r = q == 0 ? r0 : q == 1 ? r1 : q == 2 ? r2 : r3;
            acc[0] += bf2f_lo(r.x);
            acc[1] += bf2f_hi(r.x);
            acc[2] += bf2f_lo(r.y);
            acc[3] += bf2f_hi(r.y);
            acc[4] += bf2f_lo(r.z);
            acc[5] += bf2f_hi(r.z);
            acc[6] += bf2f_lo(r.w);
            acc[7] += bf2f_hi(r.w);
        }
    }

    // reduce the 4 lane-groups (XOR bits 5 and 4 of lane id)
#pragma unroll
    for (int j = 0; j < 8; j++) {
        acc[j] += __shfl_xor(acc[j], 32);
        acc[j] += __shfl_xor(acc[j], 16);
    }

    // tail: self-loop (m'[v]) + dis[v] scale + bias + relu + residual
    const size_t vrow = (size_t)v * 128 + fl;
    float dv = dis[v];
    uint4 mv = *(const uint4*)&m[vrow];
    float4 b0 = *(const float4*)&bias[fl];
    float4 b1 = *(const float4*)&bias[fl + 4];
    float mvf[8] = {bf2f_lo(mv.x), bf2f_hi(mv.x), bf2f_lo(mv.y), bf2f_hi(mv.y),
                    bf2f_lo(mv.z), bf2f_hi(mv.z), bf2f_lo(mv.w), bf2f_hi(mv.w)};
    float bb[8] = {b0.x, b0.y, b0.z, b0.w, b1.x, b1.y, b1.z, b1.w};
    float rr[8];
    if (RES_F32) {
        const float* rp = (const float*)res_ + (size_t)v * 128 + fl;
        float4 q0 = *(const float4*)rp;
        float4 q1 = *(const float4*)(rp + 4);
        rr[0] = q0.x; rr[1] = q0.y; rr[2] = q0.z; rr[3] = q0.w;
        rr[4] = q1.x; rr[5] = q1.y; rr[6] = q1.z; rr[7] = q1.w;
    } else {
        uint4 rv = *(const uint4*)((const unsigned short*)res_ + vrow);
        rr[0] = bf2f_lo(rv.x); rr[1] = bf2f_hi(rv.x);
        rr[2] = bf2f_lo(rv.y); rr[3] = bf2f_hi(rv.y);
        rr[4] = bf2f_lo(rv.z); rr[5] = bf2f_hi(rv.z);
        rr[6] = bf2f_lo(rv.w); rr[7] = bf2f_hi(rv.w);
    }
    unsigned short po[8];
#pragma unroll
    for (int j = 0; j < 8; j++) {
        float sum = acc[j] + mvf[j];
        float t = fmaxf(fmaf(sum, dv, bb[j]), 0.f) + rr[j];
        po[j] = f2bf(t);
    }
    if (g == 0) {
        uint4 o;
        o.x = (unsigned)po[0] | ((unsigned)po[1] << 16);
        o.y = (unsigned)po[2] | ((unsigned)po[3] << 16);
        o.z = (unsigned)po[4] | ((unsigned)po[5] << 16);
        o.w = (unsigned)po[6] | ((unsigned)po[7] << 16);
        *(uint4*)&hout[vrow] = o;
    }
}

// ---------------- host ----------------

extern "C" void kernel_launch(void* const* d_in, const int* in_sizes, int n_in,
                              void* d_out, int out_size, void* d_ws, size_t ws_size,
                              hipStream_t stream) {
    const float* x   = (const float*)d_in[0];
    const int*   ei  = (const int*)d_in[1];   // [2,E] int32
    const float* W1  = (const float*)d_in[2];
    const float* b1  = (const float*)d_in[3];
    const float* W2  = (const float*)d_in[4];
    const float* b2  = (const float*)d_in[5];
    const float* WL  = (const float*)d_in[6];
    const float* bl  = (const float*)d_in[7];
    float* out = (float*)d_out;

    const int* esrc = ei;
    const int* edst = ei + EE;

    char* w = (char*)d_ws;
    auto alloc = [&](size_t bytes) -> char* {
        char* p = w;
        w += (bytes + 255) & ~(size_t)255;
        return p;
    };
    int*   cnt     = (int*)alloc((size_t)NN * 4);
    int*   row_ptr = (int*)alloc((size_t)NN * 4);
    int2*  rc      = (int2*)alloc((size_t)NN * 8);
    float* dis     = (float*)alloc((size_t)NN * 4);
    int*   S       = (int*)alloc(1024 * 4);
    int*   rank    = (int*)alloc((size_t)EE * 4);
    int*   csr     = (int*)alloc((size_t)EE * 4);
    unsigned short* W1b = (unsigned short*)alloc(128 * 128 * 2);
    unsigned short* W2b = (unsigned short*)alloc(128 * 128 * 2);
    unsigned short* WLb = (unsigned short*)alloc(64 * 128 * 2);
    unsigned short* A   = (unsigned short*)alloc((size_t)(NN + 1) * 128 * 2);  // m' + zero row
    unsigned short* B   = (unsigned short*)alloc((size_t)NN * 128 * 2);        // h

    const int nb_n  = (NN + 255) / 256;
    const int nb_e8 = (EE / 8 + 255) / 256;
    const int nb_s1 = (NN + 1023) / 1024;  // 98

    // degree + per-edge arrival rank
    k_zero_int<<<nb_n, 256, 0, stream>>>(cnt, NN);
    k_count_rank<<<nb_e8, 256, 0, stream>>>(edst, cnt, rank);

    // row_ptr scan (+rc pack, +dis, +zero row of A)
    k_scan1<<<nb_s1, 1024, 0, stream>>>(cnt, row_ptr, S);
    k_scan2<<<1, 128, 0, stream>>>(S, nb_s1);
    k_scan3<<<nb_n, 256, 0, stream>>>(row_ptr, rc, S, cnt, dis,
                                      (unsigned int*)(A + (size_t)NN * 128));

    // CSR place (no atomics)
    k_fill2<<<nb_e8, 256, 0, stream>>>(esrc, edst, rank, row_ptr, csr);

    // weights fp32 -> bf16 (single launch)
    k_cvt_w<<<40, 256, 0, stream>>>(W1, W2, WL, W1b, W2b, WLb);

    const int nb_g   = (NN + 63) / 64;     // 1563
    const int nb_agg = (NN + 3) / 4;       // 25000

    // layer 1: m1' = (x @ W1.T)*dis ; h1 = relu(dis*(sum+self)+b1) + x -> B
    k_gemm_mfma<128, true, true, true><<<nb_g, 256, 0, stream>>>(x, W1b, nullptr, dis, A, NN);
    k_agg<true><<<nb_agg, 256, 0, stream>>>(A, rc, csr, dis, b1, x, B);

    // layer 2: m2' = (h1 @ W2.T)*dis ; h2 = relu(...)+h1 -> B (in place)
    k_gemm_mfma<128, false, true, true><<<nb_g, 256, 0, stream>>>(B, W2b, nullptr, dis, A, NN);
    k_agg<false><<<nb_agg, 256, 0, stream>>>(A, rc, csr, dis, b2, B, B);

    // head: out = h2 @ Wlin.T + blin (fp32 out)
    k_gemm_mfma<64, false, false, false><<<nb_g, 256, 0, stream>>>(B, WLb, bl, nullptr, out, NN);
}